// Round 1
// baseline (311.509 us; speedup 1.0000x reference)
//
#include <hip/hip_runtime.h>
#include <stdint.h>

typedef unsigned short u16;
typedef unsigned int   u32;
typedef __attribute__((ext_vector_type(8))) short bf16x8;
typedef __attribute__((ext_vector_type(4))) float f32x4;

__device__ __forceinline__ float bflo(u32 u){ return __uint_as_float(u << 16); }
__device__ __forceinline__ u32 f2bf(float f){
  u32 u = __float_as_uint(f);
  return (u + 0x7fffu + ((u >> 16) & 1u)) >> 16;
}
__device__ __forceinline__ float qbf(float f){ return __uint_as_float(f2bf(f) << 16); }

__global__ void k_zero(int* __restrict__ c, int N){
  int i = blockIdx.x * 256 + threadIdx.x;
  if (i < N) c[i] = 0;
}

// exclusive scan over cnt[N]: block-local + block sums + add-back
__global__ void k_scan1(int* __restrict__ cnt, int* __restrict__ bsum, int N){
  __shared__ int sh[256];
  int blk = blockIdx.x, tid = threadIdx.x;
  int base = blk * 1024 + tid * 4;
  int v0 = (base + 0 < N) ? cnt[base + 0] : 0;
  int v1 = (base + 1 < N) ? cnt[base + 1] : 0;
  int v2 = (base + 2 < N) ? cnt[base + 2] : 0;
  int v3 = (base + 3 < N) ? cnt[base + 3] : 0;
  int tot = v0 + v1 + v2 + v3;
  sh[tid] = tot;
  __syncthreads();
  for (int off = 1; off < 256; off <<= 1){
    int t2 = (tid >= off) ? sh[tid - off] : 0;
    __syncthreads();
    sh[tid] += t2;
    __syncthreads();
  }
  int excl = sh[tid] - tot;
  if (base + 0 < N) cnt[base + 0] = excl;
  if (base + 1 < N) cnt[base + 1] = excl + v0;
  if (base + 2 < N) cnt[base + 2] = excl + v0 + v1;
  if (base + 3 < N) cnt[base + 3] = excl + v0 + v1 + v2;
  if (tid == 255) bsum[blk] = sh[255];
}

__global__ void k_scan2(const int* __restrict__ bsum, int* __restrict__ boff, int NB){
  __shared__ int sh[512];
  int tid = threadIdx.x;
  int v = (tid < NB) ? bsum[tid] : 0;
  sh[tid] = v;
  __syncthreads();
  for (int off = 1; off < 512; off <<= 1){
    int t2 = (tid >= off) ? sh[tid - off] : 0;
    __syncthreads();
    sh[tid] += t2;
    __syncthreads();
  }
  boff[tid] = sh[tid] - v;
}

__global__ void k_scan3(int* __restrict__ cnt, const int* __restrict__ boff, int N){
  int add = boff[blockIdx.x];
  int base = blockIdx.x * 1024 + threadIdx.x * 4;
  #pragma unroll
  for (int q = 0; q < 4; q++)
    if (base + q < N) cnt[base + q] += add;
}

// Fused MFMA MLP (2 tiles = 32 edges / wave-iter) + fast-math gate.
// Writes per-edge 13-bit code linearly (no position atomics) and does the
// row histogram with fire-and-forget atomics (edges + rand entries).
__global__ void __launch_bounds__(256) k_mlp_hist(
    const u16* __restrict__ emb, const u16* __restrict__ W1,
    const u16* __restrict__ b1, const u16* __restrict__ W2,
    const u16* __restrict__ b2,
    const int* __restrict__ src, const int* __restrict__ dst,
    const u16* __restrict__ eps_u, const u16* __restrict__ rb_u,
    const int* __restrict__ rand0,
    int* __restrict__ cnt, u16* __restrict__ codes,
    int E, int R, int ntp)
{
  int lane = threadIdx.x & 63;
  int c    = lane & 15;
  int quad = lane >> 4;
  int wid  = blockIdx.x * 4 + (threadIdx.x >> 6);
  int wstride = gridDim.x * 4;

  // rand-entry histogram: independent work, no return dependency
  {
    int gtid = blockIdx.x * 256 + threadIdx.x;
    int gsz  = gridDim.x * 256;
    for (int i = gtid; i < R; i += gsz) atomicAdd(&cnt[rand0[i]], 1);
  }

  bf16x8 bfr[4][4];
  #pragma unroll
  for (int ks = 0; ks < 4; ks++)
    #pragma unroll
    for (int t = 0; t < 4; t++)
      bfr[ks][t] = *(const bf16x8*)(W1 + (size_t)(t*16 + c)*128 + ks*32 + quad*8);

  float b1v[4], w2v[4];
  #pragma unroll
  for (int t = 0; t < 4; t++){
    b1v[t] = bflo((u32)b1[t*16 + c]);
    w2v[t] = bflo((u32)W2[t*16 + c]);
  }
  float b2v = bflo((u32)b2[0]);

  for (int tp = wid; tp < ntp; tp += wstride){
    int e_base = tp * 32;
    // lanes 0..31 hold src[e_base+lane]; lanes 32..63 hold dst[e_base+lane-32]
    int idx = e_base + (lane & 31);
    if (idx >= E) idx = E - 1;
    int nd = (lane < 32) ? src[idx] : dst[idx];
    if (lane < 32 && (e_base + lane) < E) atomicAdd(&cnt[nd], 1);

    int s0 = __shfl(nd, c),      d0 = __shfl(nd, 32 + c);
    int s1 = __shfl(nd, 16 + c), d1 = __shfl(nd, 48 + c);

    // issue all 8 gathers before any MFMA (max memory-level parallelism)
    bf16x8 a0[4], a1[4];
    #pragma unroll
    for (int ks = 0; ks < 4; ks++){
      a0[ks] = *(const bf16x8*)(emb + (size_t)(ks < 2 ? s0 : d0) * 64 + (ks & 1) * 32 + quad * 8);
      a1[ks] = *(const bf16x8*)(emb + (size_t)(ks < 2 ? s1 : d1) * 64 + (ks & 1) * 32 + quad * 8);
    }

    f32x4 acc0[4], acc1[4];
    #pragma unroll
    for (int t = 0; t < 4; t++){
      acc0[t] = (f32x4){0.f,0.f,0.f,0.f};
      acc1[t] = (f32x4){0.f,0.f,0.f,0.f};
    }
    #pragma unroll
    for (int ks = 0; ks < 4; ks++){
      #pragma unroll
      for (int t = 0; t < 4; t++){
        acc0[t] = __builtin_amdgcn_mfma_f32_16x16x32_bf16(a0[ks], bfr[ks][t], acc0[t], 0, 0, 0);
        acc1[t] = __builtin_amdgcn_mfma_f32_16x16x32_bf16(a1[ks], bfr[ks][t], acc1[t], 0, 0, 0);
      }
    }

    float pr0[4], pr1[4];
    #pragma unroll
    for (int r = 0; r < 4; r++){
      float h0 = fmaxf(acc0[0][r] + b1v[0], 0.f);
      float h1 = fmaxf(acc0[1][r] + b1v[1], 0.f);
      float h2 = fmaxf(acc0[2][r] + b1v[2], 0.f);
      float h3 = fmaxf(acc0[3][r] + b1v[3], 0.f);
      pr0[r] = h0*w2v[0] + h1*w2v[1] + h2*w2v[2] + h3*w2v[3];
      float g0 = fmaxf(acc1[0][r] + b1v[0], 0.f);
      float g1 = fmaxf(acc1[1][r] + b1v[1], 0.f);
      float g2 = fmaxf(acc1[2][r] + b1v[2], 0.f);
      float g3 = fmaxf(acc1[3][r] + b1v[3], 0.f);
      pr1[r] = g0*w2v[0] + g1*w2v[1] + g2*w2v[2] + g3*w2v[3];
    }
    #pragma unroll
    for (int d = 1; d < 16; d <<= 1){
      #pragma unroll
      for (int r = 0; r < 4; r++){
        pr0[r] += __shfl_xor(pr0[r], d);
        pr1[r] += __shfl_xor(pr1[r], d);
      }
    }

    // 32 active lanes (c<8 in each quad) -> one edge each, coalesced u16 write
    if (c < 8){
      int tile = c >> 2, r = c & 3;
      int e = e_base + tile * 16 + quad * 4 + r;
      if (e < E){
        float pv0 = (r==0)?pr0[0]:(r==1)?pr0[1]:(r==2)?pr0[2]:pr0[3];
        float pv1 = (r==0)?pr1[0]:(r==1)?pr1[1]:(r==2)?pr1[2]:pr1[3];
        float logit = (tile ? pv1 : pv0) + b2v;
        float ue  = bflo((u32)eps_u[e]);
        float eps = fmaf(-0.9998f, ue, 0.9999f);
        float gate = (__log2f(eps) - __log2f(1.0f - eps)) * 0.69314718f + logit;
        gate = fminf(fmaxf(gate, -4.59511985f), 4.59511985f);
        float uu = fminf(fmaxf(bflo((u32)rb_u[e]), 1e-7f), 1.0f - 1e-7f);
        float lu = (__log2f(uu) - __log2f(1.0f - uu)) * 0.69314718f;
        float l  = (gate + lu) * (1.0f / 0.9f);
        float ee = __builtin_amdgcn_exp2f(-l * 1.44269504f);
        float val = 1.0f / (1.0f + ee);
        u32 h = f2bf(val);
        u32 code = (h >= 8192u) ? (h - 8192u) : 0u;
        codes[e] = (u16)code;
      }
    }
  }
}

// position-atomic + packed write for ALL M entries, full-lane occupancy
__global__ void k_scatter_all(const int* __restrict__ src, const int* __restrict__ dst,
                              const u16* __restrict__ codes,
                              const int* __restrict__ rand0, const int* __restrict__ rand1,
                              int* __restrict__ cursor, u32* __restrict__ packed,
                              int E, int M){
  int i = blockIdx.x * 256 + threadIdx.x;
  if (i >= M) return;
  int row, col; u32 code;
  if (i < E){
    row = src[i]; col = dst[i]; code = (u32)codes[i];
  } else {
    row = rand0[i - E]; col = rand1[i - E]; code = 7501u;  // bf16(0.05) code
  }
  int pos = atomicAdd(&cursor[row], 1);
  packed[pos] = ((u32)col << 13) | code;
}

// per-row insertion sort by packed (== by col), coalesce dups, emit FLOAT32
__global__ void k_emit(const int* __restrict__ cursor, u32* __restrict__ packed,
                       float* __restrict__ out, int N, int M){
  int r = blockIdx.x * 256 + threadIdx.x;
  if (r >= N) return;
  int b = (r == 0) ? 0 : cursor[r - 1];
  int e = cursor[r];
  for (int i = b + 1; i < e; i++){
    u32 p = packed[i];
    int j = i - 1;
    while (j >= b && packed[j] > p){ packed[j+1] = packed[j]; j--; }
    packed[j+1] = p;
  }
  float rf = qbf((float)r);
  int i = b;
  while (i < e){
    u32 p = packed[i];
    u32 col = p >> 13;
    u32 lo  = p & 8191u;
    float sum = __uint_as_float((lo ? lo + 8192u : 0u) << 16);
    int j = i + 1;
    while (j < e && (packed[j] >> 13) == col){
      u32 l2 = packed[j] & 8191u;
      sum += __uint_as_float((l2 ? l2 + 8192u : 0u) << 16);
      j++;
    }
    float cf = qbf((float)col);
    out[i] = rf; out[M + i] = cf; out[2 * M + i] = qbf(sum);
    for (int q = i + 1; q < j; q++){
      out[q] = rf; out[M + q] = cf; out[2 * M + q] = 0.f;
    }
    i = j;
  }
}

extern "C" void kernel_launch(void* const* d_in, const int* in_sizes, int n_in,
                              void* d_out, int out_size, void* d_ws, size_t ws_size,
                              hipStream_t stream){
  (void)n_in; (void)out_size; (void)ws_size;
  const u16* all_emb = (const u16*)d_in[0];
  const u16* W1   = (const u16*)d_in[1];
  const u16* b1   = (const u16*)d_in[2];
  const u16* W2   = (const u16*)d_in[3];
  const u16* b2   = (const u16*)d_in[4];
  const int* edge_index = (const int*)d_in[5];
  const int* rand_idx   = (const int*)d_in[6];
  const u16* eps_u = (const u16*)d_in[7];
  const u16* rb_u  = (const u16*)d_in[8];

  int N = in_sizes[0] / 64;
  int E = in_sizes[5] / 2;
  int R = in_sizes[6] / 2;
  int M = E + R;
  const int* src   = edge_index;
  const int* dst   = edge_index + E;
  const int* rand0 = rand_idx;
  const int* rand1 = rand_idx + R;

  // workspace: cnt[N] + bsum[512] + boff[512] + packed[M] + codes[E] (~7.6 MB)
  int* cnt  = (int*)d_ws;
  int* bsum = cnt + N;
  int* boff = bsum + 512;
  u32* packed = (u32*)(boff + 512);
  u16* codes  = (u16*)(packed + M);

  k_zero<<<(N + 255) / 256, 256, 0, stream>>>(cnt, N);
  int ntp = (E + 31) / 32;
  k_mlp_hist<<<2048, 256, 0, stream>>>(all_emb, W1, b1, W2, b2, src, dst,
                                       eps_u, rb_u, rand0, cnt, codes, E, R, ntp);
  int NB = (N + 1023) / 1024;
  k_scan1<<<NB, 256, 0, stream>>>(cnt, bsum, N);
  k_scan2<<<1, 512, 0, stream>>>(bsum, boff, NB);
  k_scan3<<<NB, 256, 0, stream>>>(cnt, boff, N);
  k_scatter_all<<<(M + 255) / 256, 256, 0, stream>>>(src, dst, codes, rand0, rand1,
                                                     cnt, packed, E, M);
  k_emit<<<(N + 255) / 256, 256, 0, stream>>>(cnt, packed, (float*)d_out, N, M);
}

// Round 2
// 271.974 us; speedup vs baseline: 1.1454x; 1.1454x over previous
//
#include <hip/hip_runtime.h>
#include <stdint.h>

typedef unsigned short u16;
typedef unsigned int   u32;
typedef __attribute__((ext_vector_type(8))) short bf16x8;
typedef __attribute__((ext_vector_type(4))) float f32x4;

__device__ __forceinline__ float bflo(u32 u){ return __uint_as_float(u << 16); }
__device__ __forceinline__ u32 f2bf(float f){
  u32 u = __float_as_uint(f);
  return (u + 0x7fffu + ((u >> 16) & 1u)) >> 16;
}
__device__ __forceinline__ float qbf(float f){ return __uint_as_float(f2bf(f) << 16); }

__global__ void k_zero(int* __restrict__ c, int N){
  int i = blockIdx.x * 256 + threadIdx.x;
  if (i < N) c[i] = 0;
}

// exclusive scan over per-row totals (sum of 8 privatized copies).
// reads cnt8[8][N], writes exclusive row starts into rowbase[N].
__global__ void k_scan1(const int* __restrict__ cnt8, int* __restrict__ rowbase,
                        int* __restrict__ bsum, int N){
  __shared__ int sh[256];
  int blk = blockIdx.x, tid = threadIdx.x;
  int base = blk * 1024 + tid * 4;
  int v0 = 0, v1 = 0, v2 = 0, v3 = 0;
  #pragma unroll
  for (int g = 0; g < 8; g++){
    const int* cg = cnt8 + (size_t)g * N;
    if (base + 0 < N) v0 += cg[base + 0];
    if (base + 1 < N) v1 += cg[base + 1];
    if (base + 2 < N) v2 += cg[base + 2];
    if (base + 3 < N) v3 += cg[base + 3];
  }
  int tot = v0 + v1 + v2 + v3;
  sh[tid] = tot;
  __syncthreads();
  for (int off = 1; off < 256; off <<= 1){
    int t2 = (tid >= off) ? sh[tid - off] : 0;
    __syncthreads();
    sh[tid] += t2;
    __syncthreads();
  }
  int excl = sh[tid] - tot;
  if (base + 0 < N) rowbase[base + 0] = excl;
  if (base + 1 < N) rowbase[base + 1] = excl + v0;
  if (base + 2 < N) rowbase[base + 2] = excl + v0 + v1;
  if (base + 3 < N) rowbase[base + 3] = excl + v0 + v1 + v2;
  if (tid == 255) bsum[blk] = sh[255];
}

__global__ void k_scan2(const int* __restrict__ bsum, int* __restrict__ boff, int NB){
  __shared__ int sh[512];
  int tid = threadIdx.x;
  int v = (tid < NB) ? bsum[tid] : 0;
  sh[tid] = v;
  __syncthreads();
  for (int off = 1; off < 512; off <<= 1){
    int t2 = (tid >= off) ? sh[tid - off] : 0;
    __syncthreads();
    sh[tid] += t2;
    __syncthreads();
  }
  boff[tid] = sh[tid] - v;
}

// add-back block offsets AND convert cnt8 copies to absolute segment bases:
// cnt8[g][r] <- rowbase[r] + sum_{j<g} cnt8[j][r]; rowbase[r] <- final start.
__global__ void k_scan3(int* __restrict__ rowbase, const int* __restrict__ boff,
                        int* __restrict__ cnt8, int N){
  int add = boff[blockIdx.x];
  int base = blockIdx.x * 1024 + threadIdx.x * 4;
  #pragma unroll
  for (int q = 0; q < 4; q++){
    int r = base + q;
    if (r < N){
      int run = rowbase[r] + add;
      rowbase[r] = run;
      #pragma unroll
      for (int g = 0; g < 8; g++){
        int* p = cnt8 + (size_t)g * N + r;
        int t = *p;
        *p = run;
        run += t;
      }
    }
  }
}

// Fused MFMA MLP (2 tiles = 32 edges / wave-iter) + fast-math gate.
// Histogram with XCD-privatized copies (g = blockIdx&7); the rank-returning
// atomic hides under the emb-gather/MFMA latency. Stores rnk16 = g<<13|rank.
__global__ void __launch_bounds__(256) k_mlp_hist(
    const u16* __restrict__ emb, const u16* __restrict__ W1,
    const u16* __restrict__ b1, const u16* __restrict__ W2,
    const u16* __restrict__ b2,
    const int* __restrict__ src, const int* __restrict__ dst,
    const u16* __restrict__ eps_u, const u16* __restrict__ rb_u,
    const int* __restrict__ rand0,
    int* __restrict__ cnt8, u16* __restrict__ codes, u16* __restrict__ rnk16,
    int E, int R, int N, int ntp)
{
  int lane = threadIdx.x & 63;
  int c    = lane & 15;
  int quad = lane >> 4;
  int wid  = blockIdx.x * 4 + (threadIdx.x >> 6);
  int wstride = gridDim.x * 4;
  int g = blockIdx.x & 7;
  int* __restrict__ gcnt = cnt8 + (size_t)g * N;
  u32 gtag = (u32)g << 13;

  // rand-entry histogram: independent work, overlapped with everything below
  {
    int gtid = blockIdx.x * 256 + threadIdx.x;
    int gsz  = gridDim.x * 256;
    for (int i = gtid; i < R; i += gsz){
      int row = rand0[i];
      int rk = atomicAdd(&gcnt[row], 1);
      rnk16[E + i] = (u16)(gtag | (u32)rk);
    }
  }

  bf16x8 bfr[4][4];
  #pragma unroll
  for (int ks = 0; ks < 4; ks++)
    #pragma unroll
    for (int t = 0; t < 4; t++)
      bfr[ks][t] = *(const bf16x8*)(W1 + (size_t)(t*16 + c)*128 + ks*32 + quad*8);

  float b1v[4], w2v[4];
  #pragma unroll
  for (int t = 0; t < 4; t++){
    b1v[t] = bflo((u32)b1[t*16 + c]);
    w2v[t] = bflo((u32)W2[t*16 + c]);
  }
  float b2v = bflo((u32)b2[0]);

  for (int tp = wid; tp < ntp; tp += wstride){
    int e_base = tp * 32;
    // lanes 0..31 hold src[e_base+lane]; lanes 32..63 hold dst[e_base+lane-32]
    int idx = e_base + (lane & 31);
    if (idx >= E) idx = E - 1;
    int nd = (lane < 32) ? src[idx] : dst[idx];
    {
      int e = e_base + lane;
      if (lane < 32 && e < E){
        int rk = atomicAdd(&gcnt[nd], 1);
        rnk16[e] = (u16)(gtag | (u32)rk);
      }
    }

    int s0 = __shfl(nd, c),      d0 = __shfl(nd, 32 + c);
    int s1 = __shfl(nd, 16 + c), d1 = __shfl(nd, 48 + c);

    // issue all 8 gathers before any MFMA (max memory-level parallelism)
    bf16x8 a0[4], a1[4];
    #pragma unroll
    for (int ks = 0; ks < 4; ks++){
      a0[ks] = *(const bf16x8*)(emb + (size_t)(ks < 2 ? s0 : d0) * 64 + (ks & 1) * 32 + quad * 8);
      a1[ks] = *(const bf16x8*)(emb + (size_t)(ks < 2 ? s1 : d1) * 64 + (ks & 1) * 32 + quad * 8);
    }

    f32x4 acc0[4], acc1[4];
    #pragma unroll
    for (int t = 0; t < 4; t++){
      acc0[t] = (f32x4){0.f,0.f,0.f,0.f};
      acc1[t] = (f32x4){0.f,0.f,0.f,0.f};
    }
    #pragma unroll
    for (int ks = 0; ks < 4; ks++){
      #pragma unroll
      for (int t = 0; t < 4; t++){
        acc0[t] = __builtin_amdgcn_mfma_f32_16x16x32_bf16(a0[ks], bfr[ks][t], acc0[t], 0, 0, 0);
        acc1[t] = __builtin_amdgcn_mfma_f32_16x16x32_bf16(a1[ks], bfr[ks][t], acc1[t], 0, 0, 0);
      }
    }

    float pr0[4], pr1[4];
    #pragma unroll
    for (int r = 0; r < 4; r++){
      float h0 = fmaxf(acc0[0][r] + b1v[0], 0.f);
      float h1 = fmaxf(acc0[1][r] + b1v[1], 0.f);
      float h2 = fmaxf(acc0[2][r] + b1v[2], 0.f);
      float h3 = fmaxf(acc0[3][r] + b1v[3], 0.f);
      pr0[r] = h0*w2v[0] + h1*w2v[1] + h2*w2v[2] + h3*w2v[3];
      float g0 = fmaxf(acc1[0][r] + b1v[0], 0.f);
      float g1 = fmaxf(acc1[1][r] + b1v[1], 0.f);
      float g2 = fmaxf(acc1[2][r] + b1v[2], 0.f);
      float g3 = fmaxf(acc1[3][r] + b1v[3], 0.f);
      pr1[r] = g0*w2v[0] + g1*w2v[1] + g2*w2v[2] + g3*w2v[3];
    }
    #pragma unroll
    for (int d = 1; d < 16; d <<= 1){
      #pragma unroll
      for (int r = 0; r < 4; r++){
        pr0[r] += __shfl_xor(pr0[r], d);
        pr1[r] += __shfl_xor(pr1[r], d);
      }
    }

    // 32 active lanes (c<8 in each quad) -> one edge each, coalesced u16 write
    if (c < 8){
      int tile = c >> 2, r = c & 3;
      int e = e_base + tile * 16 + quad * 4 + r;
      if (e < E){
        float pv0 = (r==0)?pr0[0]:(r==1)?pr0[1]:(r==2)?pr0[2]:pr0[3];
        float pv1 = (r==0)?pr1[0]:(r==1)?pr1[1]:(r==2)?pr1[2]:pr1[3];
        float logit = (tile ? pv1 : pv0) + b2v;
        float ue  = bflo((u32)eps_u[e]);
        float eps = fmaf(-0.9998f, ue, 0.9999f);
        float gate = (__log2f(eps) - __log2f(1.0f - eps)) * 0.69314718f + logit;
        gate = fminf(fmaxf(gate, -4.59511985f), 4.59511985f);
        float uu = fminf(fmaxf(bflo((u32)rb_u[e]), 1e-7f), 1.0f - 1e-7f);
        float lu = (__log2f(uu) - __log2f(1.0f - uu)) * 0.69314718f;
        float l  = (gate + lu) * (1.0f / 0.9f);
        float ee = __builtin_amdgcn_exp2f(-l * 1.44269504f);
        float val = 1.0f / (1.0f + ee);
        u32 h = f2bf(val);
        u32 code = (h >= 8192u) ? (h - 8192u) : 0u;
        codes[e] = (u16)code;
      }
    }
  }
}

// atomic-free scatter: pos = base8[g][row] + rank
__global__ void k_scatter_all(const int* __restrict__ src, const int* __restrict__ dst,
                              const u16* __restrict__ codes, const u16* __restrict__ rnk16,
                              const int* __restrict__ rand0, const int* __restrict__ rand1,
                              const int* __restrict__ cnt8, u32* __restrict__ packed,
                              int E, int M, int N){
  int i = blockIdx.x * 256 + threadIdx.x;
  if (i >= M) return;
  int row, col; u32 code;
  if (i < E){
    row = src[i]; col = dst[i]; code = (u32)codes[i];
  } else {
    row = rand0[i - E]; col = rand1[i - E]; code = 7501u;  // bf16(0.05) code
  }
  u32 rk = (u32)rnk16[i];
  int g = (int)(rk >> 13);
  int r = (int)(rk & 8191u);
  int pos = cnt8[(size_t)g * N + row] + r;
  packed[pos] = ((u32)col << 13) | code;
}

// per-row insertion sort by packed (== by col), coalesce dups, emit FLOAT32
__global__ void k_emit(const int* __restrict__ start, u32* __restrict__ packed,
                       float* __restrict__ out, int N, int M){
  int r = blockIdx.x * 256 + threadIdx.x;
  if (r >= N) return;
  int b = start[r];
  int e = (r == N - 1) ? M : start[r + 1];
  for (int i = b + 1; i < e; i++){
    u32 p = packed[i];
    int j = i - 1;
    while (j >= b && packed[j] > p){ packed[j+1] = packed[j]; j--; }
    packed[j+1] = p;
  }
  float rf = qbf((float)r);
  int i = b;
  while (i < e){
    u32 p = packed[i];
    u32 col = p >> 13;
    u32 lo  = p & 8191u;
    float sum = __uint_as_float((lo ? lo + 8192u : 0u) << 16);
    int j = i + 1;
    while (j < e && (packed[j] >> 13) == col){
      u32 l2 = packed[j] & 8191u;
      sum += __uint_as_float((l2 ? l2 + 8192u : 0u) << 16);
      j++;
    }
    float cf = qbf((float)col);
    out[i] = rf; out[M + i] = cf; out[2 * M + i] = qbf(sum);
    for (int q = i + 1; q < j; q++){
      out[q] = rf; out[M + q] = cf; out[2 * M + q] = 0.f;
    }
    i = j;
  }
}

extern "C" void kernel_launch(void* const* d_in, const int* in_sizes, int n_in,
                              void* d_out, int out_size, void* d_ws, size_t ws_size,
                              hipStream_t stream){
  (void)n_in; (void)out_size; (void)ws_size;
  const u16* all_emb = (const u16*)d_in[0];
  const u16* W1   = (const u16*)d_in[1];
  const u16* b1   = (const u16*)d_in[2];
  const u16* W2   = (const u16*)d_in[3];
  const u16* b2   = (const u16*)d_in[4];
  const int* edge_index = (const int*)d_in[5];
  const int* rand_idx   = (const int*)d_in[6];
  const u16* eps_u = (const u16*)d_in[7];
  const u16* rb_u  = (const u16*)d_in[8];

  int N = in_sizes[0] / 64;
  int E = in_sizes[5] / 2;
  int R = in_sizes[6] / 2;
  int M = E + R;
  const int* src   = edge_index;
  const int* dst   = edge_index + E;
  const int* rand0 = rand_idx;
  const int* rand1 = rand_idx + R;

  // workspace: cnt8[8N] + rowbase[N] + bsum[512] + boff[512]
  //            + packed[M] + codes[E] + rnk16[M]   (~19.5 MB)
  int* cnt8    = (int*)d_ws;
  int* rowbase = cnt8 + (size_t)8 * N;
  int* bsum    = rowbase + N;
  int* boff    = bsum + 512;
  u32* packed  = (u32*)(boff + 512);
  u16* codes   = (u16*)(packed + M);
  u16* rnk16   = codes + E;

  int N8 = 8 * N;
  k_zero<<<(N8 + 255) / 256, 256, 0, stream>>>(cnt8, N8);
  int ntp = (E + 31) / 32;
  k_mlp_hist<<<2048, 256, 0, stream>>>(all_emb, W1, b1, W2, b2, src, dst,
                                       eps_u, rb_u, rand0, cnt8, codes, rnk16,
                                       E, R, N, ntp);
  int NB = (N + 1023) / 1024;
  k_scan1<<<NB, 256, 0, stream>>>(cnt8, rowbase, bsum, N);
  k_scan2<<<1, 512, 0, stream>>>(bsum, boff, NB);
  k_scan3<<<NB, 256, 0, stream>>>(rowbase, boff, cnt8, N);
  k_scatter_all<<<(M + 255) / 256, 256, 0, stream>>>(src, dst, codes, rnk16,
                                                     rand0, rand1, cnt8, packed,
                                                     E, M, N);
  k_emit<<<(N + 255) / 256, 256, 0, stream>>>(rowbase, packed, (float*)d_out, N, M);
}